// Round 3
// baseline (91.740 us; speedup 1.0000x reference)
//
#include <hip/hip_runtime.h>

#define NG      1024
#define W_IMG   192
#define H_IMG   192
#define HW      (W_IMG * H_IMG)
#define TILES_X 24
#define TILES_Y 24
#define NTILES  (TILES_X * TILES_Y)   // 576
#define SMAX    256                   // LDS-staged survivors per tile (fallback: global)

// workspace layout (float4): pg0[NG] | pg1[NG] | pcol[NG]
//   pg0 = (gx, gy, radii, opa_or_0)
//   pg1 = (conA, conB, conC, depth)
//   pcol= (r, g, b, 0)

// ---------------------------------------------------------------------------
// Kernel 1: per-gaussian preprocess. 16 blocks x 64 threads (1 gaussian/thread)
// ---------------------------------------------------------------------------
__global__ __launch_bounds__(64) void preprocess_kernel(
    const float* __restrict__ means3D, const float* __restrict__ scales,
    const float* __restrict__ rotations, const float* __restrict__ opacities,
    const float* __restrict__ shs, const float* __restrict__ viewm,
    const float* __restrict__ projm, const float* __restrict__ campos,
    float4* __restrict__ pg0, float4* __restrict__ pg1,
    float4* __restrict__ pcol, float* __restrict__ outp)
{
    const int i = blockIdx.x * 64 + threadIdx.x;
    if (i >= NG) return;

    const float mx = means3D[i * 3 + 0];
    const float my = means3D[i * 3 + 1];
    const float mz = means3D[i * 3 + 2];

    // ---- SH degree-3 color ----
    float dxc = mx - campos[0], dyc = my - campos[1], dzc = mz - campos[2];
    float nrm = sqrtf(dxc * dxc + dyc * dyc + dzc * dzc);
    float x = dxc / nrm, y = dyc / nrm, z = dzc / nrm;
    float xx = x * x, yy = y * y, zz = z * z;
    float xy = x * y, yz = y * z, xz = x * z;

    float basis[16];
    basis[0]  = 0.28209479177387814f;
    basis[1]  = -0.4886025119029199f * y;
    basis[2]  =  0.4886025119029199f * z;
    basis[3]  = -0.4886025119029199f * x;
    basis[4]  =  1.0925484305920792f * xy;
    basis[5]  = -1.0925484305920792f * yz;
    basis[6]  =  0.31539156525252005f * (2.f * zz - xx - yy);
    basis[7]  = -1.0925484305920792f * xz;
    basis[8]  =  0.5462742152960396f * (xx - yy);
    basis[9]  = -0.5900435899266435f * y * (3.f * xx - yy);
    basis[10] =  2.890611442640554f  * xy * z;
    basis[11] = -0.4570457994644658f * y * (4.f * zz - xx - yy);
    basis[12] =  0.3731763325901154f * z * (2.f * zz - 3.f * xx - 3.f * yy);
    basis[13] = -0.4570457994644658f * x * (4.f * zz - xx - yy);
    basis[14] =  1.445305721320277f  * z * (xx - yy);
    basis[15] = -0.5900435899266435f * x * (xx - yy - 3.f * zz);

    float sh[48];
    const float4* shv = (const float4*)shs + i * 12;
#pragma unroll
    for (int w = 0; w < 12; ++w) {
        float4 q4 = shv[w];
        sh[4 * w + 0] = q4.x; sh[4 * w + 1] = q4.y;
        sh[4 * w + 2] = q4.z; sh[4 * w + 3] = q4.w;
    }
    float cr = 0.f, cg = 0.f, cb = 0.f;
#pragma unroll
    for (int k = 0; k < 16; ++k) {
        float b = basis[k];
        cr += b * sh[3 * k + 0];
        cg += b * sh[3 * k + 1];
        cb += b * sh[3 * k + 2];
    }
    cr = fmaxf(cr + 0.5f, 0.f);
    cg = fmaxf(cg + 0.5f, 0.f);
    cb = fmaxf(cb + 0.5f, 0.f);

    // ---- cov3d = (R*S)(R*S)^T ----
    const float4 q = ((const float4*)rotations)[i];
    float qr = q.x, qx = q.y, qy = q.z, qz = q.w;
    float sx = scales[i * 3 + 0], sy = scales[i * 3 + 1], sz = scales[i * 3 + 2];
    float R00 = 1.f - 2.f * (qy * qy + qz * qz), R01 = 2.f * (qx * qy - qr * qz), R02 = 2.f * (qx * qz + qr * qy);
    float R10 = 2.f * (qx * qy + qr * qz), R11 = 1.f - 2.f * (qx * qx + qz * qz), R12 = 2.f * (qy * qz - qr * qx);
    float R20 = 2.f * (qx * qz - qr * qy), R21 = 2.f * (qy * qz + qr * qx), R22 = 1.f - 2.f * (qx * qx + qy * qy);
    float M00 = R00 * sx, M01 = R01 * sy, M02 = R02 * sz;
    float M10 = R10 * sx, M11 = R11 * sy, M12 = R12 * sz;
    float M20 = R20 * sx, M21 = R21 * sy, M22 = R22 * sz;
    float S00 = M00 * M00 + M01 * M01 + M02 * M02;
    float S01 = M00 * M10 + M01 * M11 + M02 * M12;
    float S02 = M00 * M20 + M01 * M21 + M02 * M22;
    float S11 = M10 * M10 + M11 * M11 + M12 * M12;
    float S12 = M10 * M20 + M11 * M21 + M12 * M22;
    float S22 = M20 * M20 + M21 * M21 + M22 * M22;

    // ---- view / proj transform ----
    float pv0 = viewm[0] * mx + viewm[1] * my + viewm[2]  * mz + viewm[3];
    float pv1 = viewm[4] * mx + viewm[5] * my + viewm[6]  * mz + viewm[7];
    float pv2 = viewm[8] * mx + viewm[9] * my + viewm[10] * mz + viewm[11];
    float ph0 = projm[0]  * mx + projm[1]  * my + projm[2]  * mz + projm[3];
    float ph1 = projm[4]  * mx + projm[5]  * my + projm[6]  * mz + projm[7];
    float ph3 = projm[12] * mx + projm[13] * my + projm[14] * mz + projm[15];
    float pp0 = ph0 / (ph3 + 1e-7f);
    float pp1 = ph1 / (ph3 + 1e-7f);
    float gx = ((pp0 + 1.f) * (float)W_IMG - 1.f) * 0.5f;
    float gy = ((pp1 + 1.f) * (float)H_IMG - 1.f) * 0.5f;

    float depth = pv2;
    bool in_front = depth > 0.2f;
    float tz = in_front ? depth : 1.f;
    const float lim = 1.3f * 0.5f;
    float txv = fminf(fmaxf(pv0 / tz, -lim), lim) * tz;
    float tyv = fminf(fmaxf(pv1 / tz, -lim), lim) * tz;
    const float fx = (float)W_IMG / (2.f * 0.5f);
    const float fy = (float)H_IMG / (2.f * 0.5f);
    float J00 = fx / tz, J02 = -fx * txv / (tz * tz);
    float J11 = fy / tz, J12 = -fy * tyv / (tz * tz);

    float T00 = J00 * viewm[0] + J02 * viewm[8];
    float T01 = J00 * viewm[1] + J02 * viewm[9];
    float T02 = J00 * viewm[2] + J02 * viewm[10];
    float T10 = J11 * viewm[4] + J12 * viewm[8];
    float T11 = J11 * viewm[5] + J12 * viewm[9];
    float T12 = J11 * viewm[6] + J12 * viewm[10];

    float u0 = T00 * S00 + T01 * S01 + T02 * S02;
    float u1 = T00 * S01 + T01 * S11 + T02 * S12;
    float u2 = T00 * S02 + T01 * S12 + T02 * S22;
    float v0 = T10 * S00 + T11 * S01 + T12 * S02;
    float v1 = T10 * S01 + T11 * S11 + T12 * S12;
    float v2 = T10 * S02 + T11 * S12 + T12 * S22;
    float c00 = u0 * T00 + u1 * T01 + u2 * T02;
    float c01 = u0 * T10 + u1 * T11 + u2 * T12;
    float c11 = v0 * T10 + v1 * T11 + v2 * T12;

    float a = c00 + 0.3f;
    float b = c01;
    float c = c11 + 0.3f;
    float det = a * c - b * b;
    bool pos_det = det > 0.f;
    float inv_det = pos_det ? 1.f / det : 0.f;
    float conA = c * inv_det, conB = -b * inv_det, conC = a * inv_det;
    float mid = 0.5f * (a + c);
    float lam = mid + sqrtf(fmaxf(mid * mid - det, 0.1f));
    bool visible = in_front && pos_det;
    float radii = visible ? ceilf(3.f * sqrtf(lam)) : 0.f;

    float opa = opacities[i];

    outp[3 * HW + i]              = radii;
    outp[3 * HW + NG + i]         = (radii > 0.f) ? 1.f : 0.f;
    outp[3 * HW + 2 * NG + 2 * i]     = gx;
    outp[3 * HW + 2 * NG + 2 * i + 1] = gy;

    pg0[i]  = make_float4(gx, gy, radii, visible ? opa : 0.f);
    pg1[i]  = make_float4(conA, conB, conC, depth);
    pcol[i] = make_float4(cr, cg, cb, 0.f);
}

// ---------------------------------------------------------------------------
// Kernel 2: one wave = one 8x8 tile. 576 blocks x 64 threads, 20 KB LDS
// (~8 blocks/CU resident -> tile tails overlap across blocks).
//  - cull: 16 coalesced float4 reads of pg0 (L2-resident, 16 KB array)
//  - ballot compaction, survivor records staged into LDS during compaction
//  - rank sort by (depth, original idx) == reference stable argsort
//  - serial front-to-back composite, wave-uniform LDS broadcast reads
// ---------------------------------------------------------------------------
__global__ __launch_bounds__(64) void raster_kernel(
    const float4* __restrict__ pg0, const float4* __restrict__ pg1,
    const float4* __restrict__ pcol, const float* __restrict__ bg,
    float* __restrict__ outp)
{
    __shared__ unsigned int   skey[NG];   // survivor depth bits     4 KB
    __shared__ unsigned short sgi [NG];   // survivor gaussian idx   2 KB
    __shared__ unsigned short ssrt[NG];   // rank -> survivor pos    2 KB
    __shared__ float4 sr0[SMAX];          // staged g0               4 KB
    __shared__ float4 sr1[SMAX];          // staged g1               4 KB
    __shared__ float4 sc [SMAX];          // staged color            4 KB

    const int lane  = threadIdx.x;
    const int tile  = blockIdx.x;
    const int tileX = tile % TILES_X;
    const int tileY = tile / TILES_X;
    const float tx0 = (float)(tileX * 8);
    const float ty0 = (float)(tileY * 8);

    // ---- cull + compact + stage (running base in register, no atomics) ----
    // Survivor positions are ascending in gaussian idx by construction.
    int m = 0;
#pragma unroll 4
    for (int it = 0; it < NG / 64; ++it) {
        const int g = it * 64 + lane;
        float4 g0 = pg0[g];
        bool hit = (g0.w > 0.f) &&
                   (g0.x >= tx0 - g0.z) && (g0.x <= tx0 + 7.f + g0.z) &&
                   (g0.y >= ty0 - g0.z) && (g0.y <= ty0 + 7.f + g0.z);
        unsigned long long mask = __ballot(hit);
        if (hit) {
            int pos = m + __popcll(mask & ((1ULL << lane) - 1ULL));
            float4 g1 = pg1[g];
            skey[pos] = __float_as_uint(g1.w);  // depth > 0.2 -> monotonic bits
            sgi [pos] = (unsigned short)g;
            if (pos < SMAX) {
                sr0[pos] = g0;
                sr1[pos] = g1;
                sc [pos] = pcol[g];
            }
        }
        m += __popcll(mask);
    }
    __syncthreads();   // single wave: orders LDS writes before reads

    // ---- rank sort: stable argsort by (depth, idx) ----
    for (int s = lane; s < m; s += 64) {
        const unsigned int ks = skey[s];
        int rank = 0;
        for (int j = 0; j < m; ++j) {
            unsigned int kj = skey[j];
            rank += (kj < ks || (kj == ks && j < s)) ? 1 : 0;
        }
        ssrt[rank] = (unsigned short)s;
    }
    __syncthreads();

    // ---- composite: 64 lanes = 64 pixels, serial front-to-back ----
    const int lx = lane & 7, ly = lane >> 3;
    const int pxi = tileX * 8 + lx;
    const int pyi = tileY * 8 + ly;
    const float px = (float)pxi, py = (float)pyi;

    float T = 1.f, accR = 0.f, accG = 0.f, accB = 0.f;
    for (int k = 0; k < m; ++k) {
        const int p = ssrt[k];               // wave-uniform -> broadcast
        float4 g0, g1, cl;
        if (p < SMAX) {                      // uniform branch
            g0 = sr0[p]; g1 = sr1[p]; cl = sc[p];
        } else {                             // cold fallback: >SMAX survivors
            const int gi = sgi[p];
            g0 = pg0[gi]; g1 = pg1[gi]; cl = pcol[gi];
        }
        float dx = g0.x - px, dy = g0.y - py;
        bool cover = (fabsf(dx) <= g0.z) && (fabsf(dy) <= g0.z);
        float power = -0.5f * (g1.x * dx * dx + g1.z * dy * dy) - g1.y * dx * dy;
        float alpha = fminf(0.99f, g0.w * __expf(fminf(power, 0.f)));
        bool keep = cover && (power <= 0.f) && (alpha >= (1.f / 255.f));
        alpha = keep ? alpha : 0.f;
        float w = alpha * T;
        accR += w * cl.x;
        accG += w * cl.y;
        accB += w * cl.z;
        T *= (1.f - alpha);
    }

    const int pix = pyi * W_IMG + pxi;
    outp[pix]          = accR + T * bg[0];
    outp[HW + pix]     = accG + T * bg[1];
    outp[2 * HW + pix] = accB + T * bg[2];
}

// ---------------------------------------------------------------------------
extern "C" void kernel_launch(void* const* d_in, const int* in_sizes, int n_in,
                              void* d_out, int out_size, void* d_ws, size_t ws_size,
                              hipStream_t stream)
{
    const float* means3D   = (const float*)d_in[0];
    const float* scales    = (const float*)d_in[1];
    const float* rotations = (const float*)d_in[2];
    const float* opacities = (const float*)d_in[3];
    const float* shs       = (const float*)d_in[4];
    const float* viewm     = (const float*)d_in[5];
    const float* projm     = (const float*)d_in[6];
    const float* campos    = (const float*)d_in[7];
    const float* bg        = (const float*)d_in[8];

    float*  outp = (float*)d_out;
    float4* pg0  = (float4*)d_ws;
    float4* pg1  = pg0 + NG;
    float4* pcol = pg0 + 2 * NG;

    preprocess_kernel<<<NG / 64, 64, 0, stream>>>(
        means3D, scales, rotations, opacities, shs, viewm, projm, campos,
        pg0, pg1, pcol, outp);

    raster_kernel<<<NTILES, 64, 0, stream>>>(pg0, pg1, pcol, bg, outp);
}

// Round 4
// 84.379 us; speedup vs baseline: 1.0872x; 1.0872x over previous
//
#include <hip/hip_runtime.h>

#define NG      1024
#define W_IMG   192
#define H_IMG   192
#define HW      (W_IMG * H_IMG)
#define TILES_X 24
#define TILES_Y 24
#define NTILES  (TILES_X * TILES_Y)   // 576
#define TPB     512                   // 8 waves
#define TPBK    2                     // tiles per block (4 waves each)
#define NSEG    4                     // composite chunks per tile
#define NBLK    (NTILES / TPBK)       // 288 -> one generation at 2 blocks/CU

// workspace layout (float4): pg0[NG] | pg1[NG] | pcol[NG]  (SoA planes)
//   pg0 = (gx, gy, radii, opa_or_0)
//   pg1 = (conA, conB, conC, depth)
//   pcol= (r, g, b, 0)

// ---------------------------------------------------------------------------
// Kernel 1: per-gaussian preprocess. 4 blocks x 256 threads.
// ---------------------------------------------------------------------------
__global__ __launch_bounds__(256) void preprocess_kernel(
    const float* __restrict__ means3D, const float* __restrict__ scales,
    const float* __restrict__ rotations, const float* __restrict__ opacities,
    const float* __restrict__ shs, const float* __restrict__ viewm,
    const float* __restrict__ projm, const float* __restrict__ campos,
    float4* __restrict__ pg0, float4* __restrict__ pg1,
    float4* __restrict__ pcol, float* __restrict__ outp)
{
    const int i = blockIdx.x * 256 + threadIdx.x;
    if (i >= NG) return;

    const float mx = means3D[i * 3 + 0];
    const float my = means3D[i * 3 + 1];
    const float mz = means3D[i * 3 + 2];

    // ---- SH degree-3 color ----
    float dxc = mx - campos[0], dyc = my - campos[1], dzc = mz - campos[2];
    float nrm = sqrtf(dxc * dxc + dyc * dyc + dzc * dzc);
    float x = dxc / nrm, y = dyc / nrm, z = dzc / nrm;
    float xx = x * x, yy = y * y, zz = z * z;
    float xy = x * y, yz = y * z, xz = x * z;

    float basis[16];
    basis[0]  = 0.28209479177387814f;
    basis[1]  = -0.4886025119029199f * y;
    basis[2]  =  0.4886025119029199f * z;
    basis[3]  = -0.4886025119029199f * x;
    basis[4]  =  1.0925484305920792f * xy;
    basis[5]  = -1.0925484305920792f * yz;
    basis[6]  =  0.31539156525252005f * (2.f * zz - xx - yy);
    basis[7]  = -1.0925484305920792f * xz;
    basis[8]  =  0.5462742152960396f * (xx - yy);
    basis[9]  = -0.5900435899266435f * y * (3.f * xx - yy);
    basis[10] =  2.890611442640554f  * xy * z;
    basis[11] = -0.4570457994644658f * y * (4.f * zz - xx - yy);
    basis[12] =  0.3731763325901154f * z * (2.f * zz - 3.f * xx - 3.f * yy);
    basis[13] = -0.4570457994644658f * x * (4.f * zz - xx - yy);
    basis[14] =  1.445305721320277f  * z * (xx - yy);
    basis[15] = -0.5900435899266435f * x * (xx - yy - 3.f * zz);

    float sh[48];
    const float4* shv = (const float4*)shs + i * 12;
#pragma unroll
    for (int w = 0; w < 12; ++w) {
        float4 q4 = shv[w];
        sh[4 * w + 0] = q4.x; sh[4 * w + 1] = q4.y;
        sh[4 * w + 2] = q4.z; sh[4 * w + 3] = q4.w;
    }
    float cr = 0.f, cg = 0.f, cb = 0.f;
#pragma unroll
    for (int k = 0; k < 16; ++k) {
        float b = basis[k];
        cr += b * sh[3 * k + 0];
        cg += b * sh[3 * k + 1];
        cb += b * sh[3 * k + 2];
    }
    cr = fmaxf(cr + 0.5f, 0.f);
    cg = fmaxf(cg + 0.5f, 0.f);
    cb = fmaxf(cb + 0.5f, 0.f);

    // ---- cov3d = (R*S)(R*S)^T ----
    const float4 q = ((const float4*)rotations)[i];
    float qr = q.x, qx = q.y, qy = q.z, qz = q.w;
    float sx = scales[i * 3 + 0], sy = scales[i * 3 + 1], sz = scales[i * 3 + 2];
    float R00 = 1.f - 2.f * (qy * qy + qz * qz), R01 = 2.f * (qx * qy - qr * qz), R02 = 2.f * (qx * qz + qr * qy);
    float R10 = 2.f * (qx * qy + qr * qz), R11 = 1.f - 2.f * (qx * qx + qz * qz), R12 = 2.f * (qy * qz - qr * qx);
    float R20 = 2.f * (qx * qz - qr * qy), R21 = 2.f * (qy * qz + qr * qx), R22 = 1.f - 2.f * (qx * qx + qy * qy);
    float M00 = R00 * sx, M01 = R01 * sy, M02 = R02 * sz;
    float M10 = R10 * sx, M11 = R11 * sy, M12 = R12 * sz;
    float M20 = R20 * sx, M21 = R21 * sy, M22 = R22 * sz;
    float S00 = M00 * M00 + M01 * M01 + M02 * M02;
    float S01 = M00 * M10 + M01 * M11 + M02 * M12;
    float S02 = M00 * M20 + M01 * M21 + M02 * M22;
    float S11 = M10 * M10 + M11 * M11 + M12 * M12;
    float S12 = M10 * M20 + M11 * M21 + M12 * M22;
    float S22 = M20 * M20 + M21 * M21 + M22 * M22;

    // ---- view / proj transform ----
    float pv0 = viewm[0] * mx + viewm[1] * my + viewm[2]  * mz + viewm[3];
    float pv1 = viewm[4] * mx + viewm[5] * my + viewm[6]  * mz + viewm[7];
    float pv2 = viewm[8] * mx + viewm[9] * my + viewm[10] * mz + viewm[11];
    float ph0 = projm[0]  * mx + projm[1]  * my + projm[2]  * mz + projm[3];
    float ph1 = projm[4]  * mx + projm[5]  * my + projm[6]  * mz + projm[7];
    float ph3 = projm[12] * mx + projm[13] * my + projm[14] * mz + projm[15];
    float pp0 = ph0 / (ph3 + 1e-7f);
    float pp1 = ph1 / (ph3 + 1e-7f);
    float gx = ((pp0 + 1.f) * (float)W_IMG - 1.f) * 0.5f;
    float gy = ((pp1 + 1.f) * (float)H_IMG - 1.f) * 0.5f;

    float depth = pv2;
    bool in_front = depth > 0.2f;
    float tz = in_front ? depth : 1.f;
    const float lim = 1.3f * 0.5f;
    float txv = fminf(fmaxf(pv0 / tz, -lim), lim) * tz;
    float tyv = fminf(fmaxf(pv1 / tz, -lim), lim) * tz;
    const float fx = (float)W_IMG / (2.f * 0.5f);
    const float fy = (float)H_IMG / (2.f * 0.5f);
    float J00 = fx / tz, J02 = -fx * txv / (tz * tz);
    float J11 = fy / tz, J12 = -fy * tyv / (tz * tz);

    float T00 = J00 * viewm[0] + J02 * viewm[8];
    float T01 = J00 * viewm[1] + J02 * viewm[9];
    float T02 = J00 * viewm[2] + J02 * viewm[10];
    float T10 = J11 * viewm[4] + J12 * viewm[8];
    float T11 = J11 * viewm[5] + J12 * viewm[9];
    float T12 = J11 * viewm[6] + J12 * viewm[10];

    float u0 = T00 * S00 + T01 * S01 + T02 * S02;
    float u1 = T00 * S01 + T01 * S11 + T02 * S12;
    float u2 = T00 * S02 + T01 * S12 + T02 * S22;
    float v0 = T10 * S00 + T11 * S01 + T12 * S02;
    float v1 = T10 * S01 + T11 * S11 + T12 * S12;
    float v2 = T10 * S02 + T11 * S12 + T12 * S22;
    float c00 = u0 * T00 + u1 * T01 + u2 * T02;
    float c01 = u0 * T10 + u1 * T11 + u2 * T12;
    float c11 = v0 * T10 + v1 * T11 + v2 * T12;

    float a = c00 + 0.3f;
    float b = c01;
    float c = c11 + 0.3f;
    float det = a * c - b * b;
    bool pos_det = det > 0.f;
    float inv_det = pos_det ? 1.f / det : 0.f;
    float conA = c * inv_det, conB = -b * inv_det, conC = a * inv_det;
    float mid = 0.5f * (a + c);
    float lam = mid + sqrtf(fmaxf(mid * mid - det, 0.1f));
    bool visible = in_front && pos_det;
    float radii = visible ? ceilf(3.f * sqrtf(lam)) : 0.f;

    float opa = opacities[i];

    outp[3 * HW + i]              = radii;
    outp[3 * HW + NG + i]         = (radii > 0.f) ? 1.f : 0.f;
    outp[3 * HW + 2 * NG + 2 * i]     = gx;
    outp[3 * HW + 2 * NG + 2 * i + 1] = gy;

    pg0[i]  = make_float4(gx, gy, radii, visible ? opa : 0.f);
    pg1[i]  = make_float4(conA, conB, conC, depth);
    pcol[i] = make_float4(cr, cg, cb, 0.f);
}

// ---------------------------------------------------------------------------
// Kernel 2: 288 blocks x 512 threads; 2 tiles per block, 4 waves per tile.
//  - SoA staging of all 1024 records (48 KB, coalesced; shared by both tiles)
//  - per tile-group: ballot cull + atomic-base compaction over 4 waves
//  - rank sort by (depth_bits, gauss_idx) -> stable argsort, race-proof
//  - composite: wave wg of group takes sorted chunk wg (heavy-tile tail / 4)
//  - first wave of each group combines the 4 layers front-to-back
// LDS = 72 KB -> 2 blocks/CU -> all 288 blocks resident in one generation.
// ---------------------------------------------------------------------------
__global__ __launch_bounds__(TPB) void raster_kernel(
    const float4* __restrict__ pg0, const float4* __restrict__ pg1,
    const float4* __restrict__ pcol, const float* __restrict__ bg,
    float* __restrict__ outp)
{
    __shared__ float4 sg0[NG];                     // 16 KB
    __shared__ float4 sg1[NG];                     // 16 KB
    __shared__ float4 sg2[NG];                     // 16 KB
    __shared__ unsigned int   skey[TPBK][NG];      //  8 KB survivor depth bits
    __shared__ unsigned short sgi [TPBK][NG];      //  4 KB survivor gauss idx
    __shared__ unsigned short ssrt[TPBK][NG];      //  4 KB rank -> gauss idx
    __shared__ float4 segacc[TPBK][NSEG * 64];     //  8 KB
    __shared__ int s_cnt[TPBK];

    const int t = threadIdx.x;
    if (t < TPBK) s_cnt[t] = 0;
    // ---- SoA staging: three coalesced streams, 2 float4/thread each ----
    for (int k = t; k < NG; k += TPB) {
        sg0[k] = pg0[k];
        sg1[k] = pg1[k];
        sg2[k] = pcol[k];
    }
    __syncthreads();

    const int wave = t >> 6;        // 0..7
    const int lane = t & 63;
    const int tg   = wave >> 2;     // tile group: waves 0-3 -> tile A, 4-7 -> B
    const int wg   = wave & 3;      // wave within group
    const int tile = blockIdx.x * TPBK + tg;
    const int tileX = tile % TILES_X;
    const int tileY = tile / TILES_X;
    const float tx0 = (float)(tileX * 8);
    const float ty0 = (float)(tileY * 8);

    // ---- cull + compact: wave wg covers gaussians [wg*256, wg*256+256) ----
#pragma unroll
    for (int h = 0; h < 4; ++h) {
        const int g = wg * 256 + h * 64 + lane;
        float4 g0 = sg0[g];
        bool hit = (g0.w > 0.f) &&
                   (g0.x >= tx0 - g0.z) && (g0.x <= tx0 + 7.f + g0.z) &&
                   (g0.y >= ty0 - g0.z) && (g0.y <= ty0 + 7.f + g0.z);
        unsigned long long mask = __ballot(hit);
        int base = 0;
        if (lane == 0 && mask) base = atomicAdd(&s_cnt[tg], __popcll(mask));
        base = __shfl(base, 0);
        if (hit) {
            int pos = base + __popcll(mask & ((1ULL << lane) - 1ULL));
            skey[tg][pos] = __float_as_uint(sg1[g].w);  // depth>0.2 -> monotone
            sgi [tg][pos] = (unsigned short)g;
        }
    }
    __syncthreads();

    const int m = s_cnt[tg];

    // ---- rank sort by (depth, gauss idx): stable, independent of race order
    const int lt = wg * 64 + lane;   // 0..255 within group
    for (int s = lt; s < m; s += 256) {
        const unsigned int   ks = skey[tg][s];
        const unsigned short is = sgi[tg][s];
        int rank = 0;
        for (int j = 0; j < m; ++j) {
            unsigned int kj = skey[tg][j];     // lockstep j -> LDS broadcast
            rank += (kj < ks || (kj == ks && sgi[tg][j] < is)) ? 1 : 0;
        }
        ssrt[tg][rank] = is;
    }
    __syncthreads();

    // ---- composite: wave wg takes sorted chunk wg; 64 lanes = 64 pixels ----
    const int lx = lane & 7, ly = lane >> 3;
    const int pxi = tileX * 8 + lx;
    const int pyi = tileY * 8 + ly;
    const float px = (float)pxi, py = (float)pyi;

    const int chunk = (m + NSEG - 1) / NSEG;
    const int kbeg = wg * chunk;
    const int kend = min(m, kbeg + chunk);

    float T = 1.f, accR = 0.f, accG = 0.f, accB = 0.f;
    for (int k = kbeg; k < kend; ++k) {
        const int gi = ssrt[tg][k];            // wave-uniform -> broadcast
        float4 g0 = sg0[gi];
        float4 g1 = sg1[gi];
        float4 g2 = sg2[gi];
        float dx = g0.x - px, dy = g0.y - py;
        bool cover = (fabsf(dx) <= g0.z) && (fabsf(dy) <= g0.z);
        float power = -0.5f * (g1.x * dx * dx + g1.z * dy * dy) - g1.y * dx * dy;
        float alpha = fminf(0.99f, g0.w * __expf(fminf(power, 0.f)));
        bool keep = cover && (power <= 0.f) && (alpha >= (1.f / 255.f));
        alpha = keep ? alpha : 0.f;
        float w = alpha * T;
        accR += w * g2.x;
        accG += w * g2.y;
        accB += w * g2.z;
        T *= (1.f - alpha);
    }

    segacc[tg][wg * 64 + lane] = make_float4(accR, accG, accB, T);
    __syncthreads();

    // ---- combine 4 chunk layers front-to-back (first wave of each group) ----
    if (wg == 0) {
        float Tc = 1.f, r = 0.f, g = 0.f, b = 0.f;
#pragma unroll
        for (int s2 = 0; s2 < NSEG; ++s2) {
            float4 cc = segacc[tg][s2 * 64 + lane];
            r += Tc * cc.x;
            g += Tc * cc.y;
            b += Tc * cc.z;
            Tc *= cc.w;
        }
        const int pix = pyi * W_IMG + pxi;     // same lane->pixel map
        outp[pix]          = r + Tc * bg[0];
        outp[HW + pix]     = g + Tc * bg[1];
        outp[2 * HW + pix] = b + Tc * bg[2];
    }
}

// ---------------------------------------------------------------------------
extern "C" void kernel_launch(void* const* d_in, const int* in_sizes, int n_in,
                              void* d_out, int out_size, void* d_ws, size_t ws_size,
                              hipStream_t stream)
{
    const float* means3D   = (const float*)d_in[0];
    const float* scales    = (const float*)d_in[1];
    const float* rotations = (const float*)d_in[2];
    const float* opacities = (const float*)d_in[3];
    const float* shs       = (const float*)d_in[4];
    const float* viewm     = (const float*)d_in[5];
    const float* projm     = (const float*)d_in[6];
    const float* campos    = (const float*)d_in[7];
    const float* bg        = (const float*)d_in[8];

    float*  outp = (float*)d_out;
    float4* pg0  = (float4*)d_ws;
    float4* pg1  = pg0 + NG;
    float4* pcol = pg0 + 2 * NG;

    preprocess_kernel<<<NG / 256, 256, 0, stream>>>(
        means3D, scales, rotations, opacities, shs, viewm, projm, campos,
        pg0, pg1, pcol, outp);

    raster_kernel<<<NBLK, TPB, 0, stream>>>(pg0, pg1, pcol, bg, outp);
}

// Round 5
// 82.235 us; speedup vs baseline: 1.1156x; 1.0261x over previous
//
#include <hip/hip_runtime.h>

#define NG      1024
#define W_IMG   192
#define H_IMG   192
#define HW      (W_IMG * H_IMG)
#define TILES_X 24
#define TILES_Y 24
#define NTILES  (TILES_X * TILES_Y)   // 576
#define NSEG    4                     // composite chunks per tile
#define SMAX    384                   // LDS-staged survivors (global fallback past this)

// workspace layout (float4): pg0[NG] | pg1[NG] | pcol[NG]  (SoA planes)
//   pg0 = (gx, gy, radii, opa_or_0)
//   pg1 = (conA, conB, conC, depth)
//   pcol= (r, g, b, 0)

// ---------------------------------------------------------------------------
// Kernel 1: per-gaussian preprocess. 16 blocks x 64 threads.
// ---------------------------------------------------------------------------
__global__ __launch_bounds__(64) void preprocess_kernel(
    const float* __restrict__ means3D, const float* __restrict__ scales,
    const float* __restrict__ rotations, const float* __restrict__ opacities,
    const float* __restrict__ shs, const float* __restrict__ viewm,
    const float* __restrict__ projm, const float* __restrict__ campos,
    float4* __restrict__ pg0, float4* __restrict__ pg1,
    float4* __restrict__ pcol, float* __restrict__ outp)
{
    const int i = blockIdx.x * 64 + threadIdx.x;
    if (i >= NG) return;

    const float mx = means3D[i * 3 + 0];
    const float my = means3D[i * 3 + 1];
    const float mz = means3D[i * 3 + 2];

    // ---- SH degree-3 color ----
    float dxc = mx - campos[0], dyc = my - campos[1], dzc = mz - campos[2];
    float nrm = sqrtf(dxc * dxc + dyc * dyc + dzc * dzc);
    float x = dxc / nrm, y = dyc / nrm, z = dzc / nrm;
    float xx = x * x, yy = y * y, zz = z * z;
    float xy = x * y, yz = y * z, xz = x * z;

    float basis[16];
    basis[0]  = 0.28209479177387814f;
    basis[1]  = -0.4886025119029199f * y;
    basis[2]  =  0.4886025119029199f * z;
    basis[3]  = -0.4886025119029199f * x;
    basis[4]  =  1.0925484305920792f * xy;
    basis[5]  = -1.0925484305920792f * yz;
    basis[6]  =  0.31539156525252005f * (2.f * zz - xx - yy);
    basis[7]  = -1.0925484305920792f * xz;
    basis[8]  =  0.5462742152960396f * (xx - yy);
    basis[9]  = -0.5900435899266435f * y * (3.f * xx - yy);
    basis[10] =  2.890611442640554f  * xy * z;
    basis[11] = -0.4570457994644658f * y * (4.f * zz - xx - yy);
    basis[12] =  0.3731763325901154f * z * (2.f * zz - 3.f * xx - 3.f * yy);
    basis[13] = -0.4570457994644658f * x * (4.f * zz - xx - yy);
    basis[14] =  1.445305721320277f  * z * (xx - yy);
    basis[15] = -0.5900435899266435f * x * (xx - yy - 3.f * zz);

    float sh[48];
    const float4* shv = (const float4*)shs + i * 12;
#pragma unroll
    for (int w = 0; w < 12; ++w) {
        float4 q4 = shv[w];
        sh[4 * w + 0] = q4.x; sh[4 * w + 1] = q4.y;
        sh[4 * w + 2] = q4.z; sh[4 * w + 3] = q4.w;
    }
    float cr = 0.f, cg = 0.f, cb = 0.f;
#pragma unroll
    for (int k = 0; k < 16; ++k) {
        float b = basis[k];
        cr += b * sh[3 * k + 0];
        cg += b * sh[3 * k + 1];
        cb += b * sh[3 * k + 2];
    }
    cr = fmaxf(cr + 0.5f, 0.f);
    cg = fmaxf(cg + 0.5f, 0.f);
    cb = fmaxf(cb + 0.5f, 0.f);

    // ---- cov3d = (R*S)(R*S)^T ----
    const float4 q = ((const float4*)rotations)[i];
    float qr = q.x, qx = q.y, qy = q.z, qz = q.w;
    float sx = scales[i * 3 + 0], sy = scales[i * 3 + 1], sz = scales[i * 3 + 2];
    float R00 = 1.f - 2.f * (qy * qy + qz * qz), R01 = 2.f * (qx * qy - qr * qz), R02 = 2.f * (qx * qz + qr * qy);
    float R10 = 2.f * (qx * qy + qr * qz), R11 = 1.f - 2.f * (qx * qx + qz * qz), R12 = 2.f * (qy * qz - qr * qx);
    float R20 = 2.f * (qx * qz - qr * qy), R21 = 2.f * (qy * qz + qr * qx), R22 = 1.f - 2.f * (qx * qx + qy * qy);
    float M00 = R00 * sx, M01 = R01 * sy, M02 = R02 * sz;
    float M10 = R10 * sx, M11 = R11 * sy, M12 = R12 * sz;
    float M20 = R20 * sx, M21 = R21 * sy, M22 = R22 * sz;
    float S00 = M00 * M00 + M01 * M01 + M02 * M02;
    float S01 = M00 * M10 + M01 * M11 + M02 * M12;
    float S02 = M00 * M20 + M01 * M21 + M02 * M22;
    float S11 = M10 * M10 + M11 * M11 + M12 * M12;
    float S12 = M10 * M20 + M11 * M21 + M12 * M22;
    float S22 = M20 * M20 + M21 * M21 + M22 * M22;

    // ---- view / proj transform ----
    float pv0 = viewm[0] * mx + viewm[1] * my + viewm[2]  * mz + viewm[3];
    float pv1 = viewm[4] * mx + viewm[5] * my + viewm[6]  * mz + viewm[7];
    float pv2 = viewm[8] * mx + viewm[9] * my + viewm[10] * mz + viewm[11];
    float ph0 = projm[0]  * mx + projm[1]  * my + projm[2]  * mz + projm[3];
    float ph1 = projm[4]  * mx + projm[5]  * my + projm[6]  * mz + projm[7];
    float ph3 = projm[12] * mx + projm[13] * my + projm[14] * mz + projm[15];
    float pp0 = ph0 / (ph3 + 1e-7f);
    float pp1 = ph1 / (ph3 + 1e-7f);
    float gx = ((pp0 + 1.f) * (float)W_IMG - 1.f) * 0.5f;
    float gy = ((pp1 + 1.f) * (float)H_IMG - 1.f) * 0.5f;

    float depth = pv2;
    bool in_front = depth > 0.2f;
    float tz = in_front ? depth : 1.f;
    const float lim = 1.3f * 0.5f;
    float txv = fminf(fmaxf(pv0 / tz, -lim), lim) * tz;
    float tyv = fminf(fmaxf(pv1 / tz, -lim), lim) * tz;
    const float fx = (float)W_IMG / (2.f * 0.5f);
    const float fy = (float)H_IMG / (2.f * 0.5f);
    float J00 = fx / tz, J02 = -fx * txv / (tz * tz);
    float J11 = fy / tz, J12 = -fy * tyv / (tz * tz);

    float T00 = J00 * viewm[0] + J02 * viewm[8];
    float T01 = J00 * viewm[1] + J02 * viewm[9];
    float T02 = J00 * viewm[2] + J02 * viewm[10];
    float T10 = J11 * viewm[4] + J12 * viewm[8];
    float T11 = J11 * viewm[5] + J12 * viewm[9];
    float T12 = J11 * viewm[6] + J12 * viewm[10];

    float u0 = T00 * S00 + T01 * S01 + T02 * S02;
    float u1 = T00 * S01 + T01 * S11 + T02 * S12;
    float u2 = T00 * S02 + T01 * S12 + T02 * S22;
    float v0 = T10 * S00 + T11 * S01 + T12 * S02;
    float v1 = T10 * S01 + T11 * S11 + T12 * S12;
    float v2 = T10 * S02 + T11 * S12 + T12 * S22;
    float c00 = u0 * T00 + u1 * T01 + u2 * T02;
    float c01 = u0 * T10 + u1 * T11 + u2 * T12;
    float c11 = v0 * T10 + v1 * T11 + v2 * T12;

    float a = c00 + 0.3f;
    float b = c01;
    float c = c11 + 0.3f;
    float det = a * c - b * b;
    bool pos_det = det > 0.f;
    float inv_det = pos_det ? 1.f / det : 0.f;
    float conA = c * inv_det, conB = -b * inv_det, conC = a * inv_det;
    float mid = 0.5f * (a + c);
    float lam = mid + sqrtf(fmaxf(mid * mid - det, 0.1f));
    bool visible = in_front && pos_det;
    float radii = visible ? ceilf(3.f * sqrtf(lam)) : 0.f;

    float opa = opacities[i];

    outp[3 * HW + i]              = radii;
    outp[3 * HW + NG + i]         = (radii > 0.f) ? 1.f : 0.f;
    outp[3 * HW + 2 * NG + 2 * i]     = gx;
    outp[3 * HW + 2 * NG + 2 * i + 1] = gy;

    pg0[i]  = make_float4(gx, gy, radii, visible ? opa : 0.f);
    pg1[i]  = make_float4(conA, conB, conC, depth);
    pcol[i] = make_float4(cr, cg, cb, 0.f);
}

// ---------------------------------------------------------------------------
// Kernel 2: 576 blocks x 256 threads (4 waves), one 8x8 tile per block.
//  - cull straight from global pg0 (16 KB, coalesced, L2/L3-resident)
//  - ballot + LDS-atomic compaction; survivor records gathered into LDS
//    (up to SMAX; wave-uniform global fallback past that)
//  - packed u64 key (depth_bits<<16 | gauss_idx): one compare = stable
//    (depth, idx) order, independent of cross-wave compaction race
//  - composite: wave wg takes sorted chunk wg (NSEG=4 tail split)
//  - wave 0 combines the 4 layers front-to-back
// LDS ~33 KB -> 4 blocks/CU -> all 576 blocks resident in one generation.
// ---------------------------------------------------------------------------
__global__ __launch_bounds__(256) void raster_kernel(
    const float4* __restrict__ pg0, const float4* __restrict__ pg1,
    const float4* __restrict__ pcol, const float* __restrict__ bg,
    float* __restrict__ outp)
{
    __shared__ unsigned long long skey[NG];   // (depth<<16)|gi         8 KB
    __shared__ unsigned short     ssrt[NG];   // rank -> survivor pos   2 KB
    __shared__ float4 sr0[SMAX];              // staged g0              6 KB
    __shared__ float4 sr1[SMAX];              // staged g1              6 KB
    __shared__ float4 sc [SMAX];              // staged color           6 KB
    __shared__ float4 segacc[NSEG * 64];      //                        4 KB
    __shared__ int s_cnt;

    const int t    = threadIdx.x;
    const int wave = t >> 6;
    const int lane = t & 63;
    const int tile = blockIdx.x;
    const int tileX = tile % TILES_X;
    const int tileY = tile / TILES_X;
    const float tx0 = (float)(tileX * 8);
    const float ty0 = (float)(tileY * 8);

    if (t == 0) s_cnt = 0;
    __syncthreads();

    // ---- cull + compact + gather-stage (4 gaussians per thread) ----
#pragma unroll
    for (int h = 0; h < NG / 256; ++h) {
        const int g = h * 256 + t;           // coalesced across the wave
        float4 g0 = pg0[g];
        bool hit = (g0.w > 0.f) &&
                   (g0.x >= tx0 - g0.z) && (g0.x <= tx0 + 7.f + g0.z) &&
                   (g0.y >= ty0 - g0.z) && (g0.y <= ty0 + 7.f + g0.z);
        unsigned long long mask = __ballot(hit);
        int base = 0;
        if (lane == 0 && mask) base = atomicAdd(&s_cnt, __popcll(mask));
        base = __shfl(base, 0);
        if (hit) {
            int pos = base + __popcll(mask & ((1ULL << lane) - 1ULL));
            float4 g1 = pg1[g];
            // depth > 0.2 -> positive float -> unsigned-monotone bits
            skey[pos] = ((unsigned long long)__float_as_uint(g1.w) << 16)
                        | (unsigned)g;
            if (pos < SMAX) {
                sr0[pos] = g0;
                sr1[pos] = g1;
                sc [pos] = pcol[g];
            }
        }
    }
    __syncthreads();

    const int m = s_cnt;

    // ---- rank sort: one u64 compare == stable (depth, original idx) ----
    for (int s = t; s < m; s += 256) {
        const unsigned long long ks = skey[s];
        int rank = 0;
        for (int j = 0; j < m; ++j)
            rank += (skey[j] < ks) ? 1 : 0;   // lockstep j -> LDS broadcast
        ssrt[rank] = (unsigned short)s;
    }
    __syncthreads();

    // ---- composite: wave wg takes sorted chunk wg; 64 lanes = 64 pixels ----
    const int lx = lane & 7, ly = lane >> 3;
    const int pxi = tileX * 8 + lx;
    const int pyi = tileY * 8 + ly;
    const float px = (float)pxi, py = (float)pyi;

    const int chunk = (m + NSEG - 1) / NSEG;
    const int kbeg = wave * chunk;
    const int kend = min(m, kbeg + chunk);

    float T = 1.f, accR = 0.f, accG = 0.f, accB = 0.f;
    for (int k = kbeg; k < kend; ++k) {
        const int p = ssrt[k];               // wave-uniform -> broadcast
        float4 g0, g1, cl;
        if (p < SMAX) {                      // uniform branch
            g0 = sr0[p]; g1 = sr1[p]; cl = sc[p];
        } else {                             // cold fallback (huge tile)
            const int gi = (int)(skey[p] & 0xFFFFu);
            g0 = pg0[gi]; g1 = pg1[gi]; cl = pcol[gi];
        }
        float dx = g0.x - px, dy = g0.y - py;
        bool cover = (fabsf(dx) <= g0.z) && (fabsf(dy) <= g0.z);
        float power = -0.5f * (g1.x * dx * dx + g1.z * dy * dy) - g1.y * dx * dy;
        float alpha = fminf(0.99f, g0.w * __expf(fminf(power, 0.f)));
        bool keep = cover && (power <= 0.f) && (alpha >= (1.f / 255.f));
        alpha = keep ? alpha : 0.f;
        float w = alpha * T;
        accR += w * cl.x;
        accG += w * cl.y;
        accB += w * cl.z;
        T *= (1.f - alpha);
    }

    segacc[wave * 64 + lane] = make_float4(accR, accG, accB, T);
    __syncthreads();

    // ---- combine 4 chunk layers front-to-back (wave 0) ----
    if (wave == 0) {
        float Tc = 1.f, r = 0.f, g = 0.f, b = 0.f;
#pragma unroll
        for (int s2 = 0; s2 < NSEG; ++s2) {
            float4 cc = segacc[s2 * 64 + lane];
            r += Tc * cc.x;
            g += Tc * cc.y;
            b += Tc * cc.z;
            Tc *= cc.w;
        }
        const int pix = pyi * W_IMG + pxi;   // wave 0: lane -> same pixel map
        outp[pix]          = r + Tc * bg[0];
        outp[HW + pix]     = g + Tc * bg[1];
        outp[2 * HW + pix] = b + Tc * bg[2];
    }
}

// ---------------------------------------------------------------------------
extern "C" void kernel_launch(void* const* d_in, const int* in_sizes, int n_in,
                              void* d_out, int out_size, void* d_ws, size_t ws_size,
                              hipStream_t stream)
{
    const float* means3D   = (const float*)d_in[0];
    const float* scales    = (const float*)d_in[1];
    const float* rotations = (const float*)d_in[2];
    const float* opacities = (const float*)d_in[3];
    const float* shs       = (const float*)d_in[4];
    const float* viewm     = (const float*)d_in[5];
    const float* projm     = (const float*)d_in[6];
    const float* campos    = (const float*)d_in[7];
    const float* bg        = (const float*)d_in[8];

    float*  outp = (float*)d_out;
    float4* pg0  = (float4*)d_ws;
    float4* pg1  = pg0 + NG;
    float4* pcol = pg0 + 2 * NG;

    preprocess_kernel<<<NG / 64, 64, 0, stream>>>(
        means3D, scales, rotations, opacities, shs, viewm, projm, campos,
        pg0, pg1, pcol, outp);

    raster_kernel<<<NTILES, 256, 0, stream>>>(pg0, pg1, pcol, bg, outp);
}